// Round 1
// baseline (2254.775 us; speedup 1.0000x reference)
//
#include <hip/hip_runtime.h>
#include <hip/hip_bf16.h>
#include <cstddef>

#define D_MODEL 1024
#define NHEAD   16
#define HD      64
#define BATCH   2
#define SEQ     2048
#define BH      (BATCH*NHEAD)   // 32

// ---------------------------------------------------------------------------
// K1: qkv = x @ w_qkv  (M=4096, K=1024, N=3072), scatter into Q/K/V (BH,S,HD)
// 128x128 tile, 256 threads, 8x8 microtile, BK=8, fp32 vector ALU.
// ---------------------------------------------------------------------------
__global__ __launch_bounds__(256) void gemm_qkv_kernel(
    const float* __restrict__ X, const float* __restrict__ W,
    float* __restrict__ Qo, float* __restrict__ Ko, float* __restrict__ Vo)
{
    const int KDIM = D_MODEL;     // 1024
    const int N    = 3*D_MODEL;   // 3072
    __shared__ float As[8][128];
    __shared__ float Bs[8][128];
    const int tid  = threadIdx.x;
    const int tx   = tid & 15;
    const int ty   = tid >> 4;
    const int row0 = blockIdx.y * 128;
    const int col0 = blockIdx.x * 128;
    const int a_row = tid >> 1;
    const int a_col = (tid & 1) << 2;
    const int b_row = tid >> 5;
    const int b_col = (tid & 31) << 2;
    float acc[8][8] = {};
    for (int k0 = 0; k0 < KDIM; k0 += 8) {
        float4 av = *(const float4*)&X[(size_t)(row0 + a_row)*KDIM + k0 + a_col];
        float4 bv = *(const float4*)&W[(size_t)(k0 + b_row)*N + col0 + b_col];
        As[a_col+0][a_row] = av.x;
        As[a_col+1][a_row] = av.y;
        As[a_col+2][a_row] = av.z;
        As[a_col+3][a_row] = av.w;
        *(float4*)&Bs[b_row][b_col] = bv;
        __syncthreads();
        #pragma unroll
        for (int k = 0; k < 8; ++k) {
            float a[8], b[8];
            *(float4*)&a[0] = *(const float4*)&As[k][ty*8];
            *(float4*)&a[4] = *(const float4*)&As[k][ty*8+4];
            *(float4*)&b[0] = *(const float4*)&Bs[k][tx*8];
            *(float4*)&b[4] = *(const float4*)&Bs[k][tx*8+4];
            #pragma unroll
            for (int i = 0; i < 8; ++i)
                #pragma unroll
                for (int j = 0; j < 8; ++j)
                    acc[i][j] = fmaf(a[i], b[j], acc[i][j]);
        }
        __syncthreads();
    }
    // Epilogue: scatter. cols c0+tx*8..+7 are 8-aligned so they stay inside
    // one head (HD=64) and one of {q,k,v}.
    const int cbase = col0 + tx*8;
    const int which = cbase >> 10;
    const int rem   = cbase & 1023;
    const int h     = rem >> 6;
    const int dd    = rem & 63;
    float* dstBase = (which == 0) ? Qo : (which == 1) ? Ko : Vo;
    #pragma unroll
    for (int i = 0; i < 8; ++i) {
        const int r  = row0 + ty*8 + i;
        const int bb = r >> 11;        // batch
        const int ss = r & 2047;       // seq pos
        float* dst = dstBase + ((size_t)(bb*NHEAD + h)*SEQ + ss)*HD + dd;
        *(float4*)&dst[0] = make_float4(acc[i][0], acc[i][1], acc[i][2], acc[i][3]);
        *(float4*)&dst[4] = make_float4(acc[i][4], acc[i][5], acc[i][6], acc[i][7]);
    }
}

// ---------------------------------------------------------------------------
// K2: causal flash attention, fp32. One thread per query row.
// Block = 256 threads = 256 rows of one (b,h). K/V tiles of 32 keys in LDS.
// ---------------------------------------------------------------------------
__global__ __launch_bounds__(256, 1) void attn_kernel(
    const float* __restrict__ Q, const float* __restrict__ K,
    const float* __restrict__ V, float* __restrict__ AO)
{
    __shared__ float Ks[32*64];
    __shared__ float Vs[32*64];
    const int tid = threadIdx.x;
    const int bh  = blockIdx.y;                 // 0..31
    const int row = blockIdx.x*256 + tid;       // query row within (b,h)
    const float* qp = Q + ((size_t)bh*SEQ + row)*HD;
    float q[64];
    #pragma unroll
    for (int i = 0; i < 16; ++i)
        *(float4*)&q[i*4] = *(const float4*)&qp[i*4];
    float o[64];
    #pragma unroll
    for (int d = 0; d < 64; ++d) o[d] = 0.f;
    float m = -1e30f, l = 0.f;
    const int kend = blockIdx.x*256 + 256;      // max key+1 needed by this block
    for (int kt = 0; kt < kend; kt += 32) {
        const float* ksrc = K + ((size_t)bh*SEQ + kt)*HD;
        const float* vsrc = V + ((size_t)bh*SEQ + kt)*HD;
        __syncthreads();                        // protect previous tile reads
        *(float4*)&Ks[tid*4]        = *(const float4*)&ksrc[tid*4];
        *(float4*)&Ks[1024 + tid*4] = *(const float4*)&ksrc[1024 + tid*4];
        *(float4*)&Vs[tid*4]        = *(const float4*)&vsrc[tid*4];
        *(float4*)&Vs[1024 + tid*4] = *(const float4*)&vsrc[1024 + tid*4];
        __syncthreads();
        if (kt <= row) {
            float s[32];
            #pragma unroll
            for (int kk = 0; kk < 32; ++kk) {
                const float* kvp = &Ks[kk*64];
                float s0 = 0.f, s1 = 0.f, s2 = 0.f, s3 = 0.f;
                #pragma unroll
                for (int d = 0; d < 16; ++d) {
                    float4 k4 = *(const float4*)&kvp[d*4];
                    s0 = fmaf(k4.x, q[d*4+0], s0);
                    s1 = fmaf(k4.y, q[d*4+1], s1);
                    s2 = fmaf(k4.z, q[d*4+2], s2);
                    s3 = fmaf(k4.w, q[d*4+3], s3);
                }
                float sv = ((s0+s1)+(s2+s3)) * 0.125f;
                s[kk] = (kt + kk > row) ? -1e30f : sv;
            }
            float mt = s[0];
            #pragma unroll
            for (int kk = 1; kk < 32; ++kk) mt = fmaxf(mt, s[kk]);
            const float mnew  = fmaxf(m, mt);
            const float alpha = __expf(m - mnew);
            float psum = 0.f;
            #pragma unroll
            for (int kk = 0; kk < 32; ++kk) { s[kk] = __expf(s[kk]-mnew); psum += s[kk]; }
            l = l*alpha + psum;
            m = mnew;
            #pragma unroll
            for (int d = 0; d < 64; ++d) o[d] *= alpha;
            #pragma unroll
            for (int kk = 0; kk < 32; ++kk) {
                const float* vvp = &Vs[kk*64];
                const float p = s[kk];
                #pragma unroll
                for (int d = 0; d < 16; ++d) {
                    float4 v4 = *(const float4*)&vvp[d*4];
                    o[d*4+0] = fmaf(p, v4.x, o[d*4+0]);
                    o[d*4+1] = fmaf(p, v4.y, o[d*4+1]);
                    o[d*4+2] = fmaf(p, v4.z, o[d*4+2]);
                    o[d*4+3] = fmaf(p, v4.w, o[d*4+3]);
                }
            }
        }
    }
    const float inv = 1.f / l;                  // l >= 1 (own key always present)
    const int bb = bh >> 4;
    const int h  = bh & 15;
    float* dst = AO + ((size_t)bb*SEQ + row)*D_MODEL + h*HD;
    #pragma unroll
    for (int i = 0; i < 16; ++i)
        *(float4*)&dst[i*4] = make_float4(o[i*4+0]*inv, o[i*4+1]*inv,
                                          o[i*4+2]*inv, o[i*4+3]*inv);
}

// ---------------------------------------------------------------------------
// K3: out = AO @ w_out  (M=4096, K=1024, N=1024)
// ---------------------------------------------------------------------------
__global__ __launch_bounds__(256) void gemm_out_kernel(
    const float* __restrict__ A, const float* __restrict__ W,
    float* __restrict__ C)
{
    const int KDIM = D_MODEL;   // 1024
    const int N    = D_MODEL;   // 1024
    __shared__ float As[8][128];
    __shared__ float Bs[8][128];
    const int tid  = threadIdx.x;
    const int tx   = tid & 15;
    const int ty   = tid >> 4;
    const int row0 = blockIdx.y * 128;
    const int col0 = blockIdx.x * 128;
    const int a_row = tid >> 1;
    const int a_col = (tid & 1) << 2;
    const int b_row = tid >> 5;
    const int b_col = (tid & 31) << 2;
    float acc[8][8] = {};
    for (int k0 = 0; k0 < KDIM; k0 += 8) {
        float4 av = *(const float4*)&A[(size_t)(row0 + a_row)*KDIM + k0 + a_col];
        float4 bv = *(const float4*)&W[(size_t)(k0 + b_row)*N + col0 + b_col];
        As[a_col+0][a_row] = av.x;
        As[a_col+1][a_row] = av.y;
        As[a_col+2][a_row] = av.z;
        As[a_col+3][a_row] = av.w;
        *(float4*)&Bs[b_row][b_col] = bv;
        __syncthreads();
        #pragma unroll
        for (int k = 0; k < 8; ++k) {
            float a[8], b[8];
            *(float4*)&a[0] = *(const float4*)&As[k][ty*8];
            *(float4*)&a[4] = *(const float4*)&As[k][ty*8+4];
            *(float4*)&b[0] = *(const float4*)&Bs[k][tx*8];
            *(float4*)&b[4] = *(const float4*)&Bs[k][tx*8+4];
            #pragma unroll
            for (int i = 0; i < 8; ++i)
                #pragma unroll
                for (int j = 0; j < 8; ++j)
                    acc[i][j] = fmaf(a[i], b[j], acc[i][j]);
        }
        __syncthreads();
    }
    #pragma unroll
    for (int i = 0; i < 8; ++i) {
        const int r = row0 + ty*8 + i;
        float* dst = C + (size_t)r*N + col0 + tx*8;
        *(float4*)&dst[0] = make_float4(acc[i][0], acc[i][1], acc[i][2], acc[i][3]);
        *(float4*)&dst[4] = make_float4(acc[i][4], acc[i][5], acc[i][6], acc[i][7]);
    }
}

// ---------------------------------------------------------------------------
extern "C" void kernel_launch(void* const* d_in, const int* in_sizes, int n_in,
                              void* d_out, int out_size, void* d_ws, size_t ws_size,
                              hipStream_t stream)
{
    const float* x     = (const float*)d_in[0];   // (2,2048,1024)
    const float* w_qkv = (const float*)d_in[1];   // (1024,3072)
    const float* w_out = (const float*)d_in[2];   // (1024,1024)
    float* out = (float*)d_out;                   // (2,2048,1024)

    const size_t per = (size_t)BH * SEQ * HD;     // 4,194,304 floats
    float* Q  = (float*)d_ws;
    float* K  = Q + per;
    float* V  = K + per;
    float* AO = V + per;                          // (B,S,D) attn output

    // qkv projection: grid = (N/128, M/128) = (24, 32)
    gemm_qkv_kernel<<<dim3(24, 32), 256, 0, stream>>>(x, w_qkv, Q, K, V);
    // causal attention: grid = (S/256, B*H) = (8, 32)
    attn_kernel<<<dim3(SEQ/256, BH), 256, 0, stream>>>(Q, K, V, AO);
    // output projection: grid = (N/128, M/128) = (8, 32)
    gemm_out_kernel<<<dim3(8, 32), 256, 0, stream>>>(AO, w_out, out);
}

// Round 2
// 1344.000 us; speedup vs baseline: 1.6777x; 1.6777x over previous
//
#include <hip/hip_runtime.h>
#include <hip/hip_bf16.h>
#include <cstddef>

#define D_MODEL 1024
#define NHEAD   16
#define HD      64
#define BATCH   2
#define SEQ     2048
#define BH      (BATCH*NHEAD)   // 32

// ---------------------------------------------------------------------------
// K1: qkv = x @ w_qkv  (M=4096, K=1024, N=3072), scatter into Q/K/V (BH,S,HD)
// 128x128 tile, 256 threads, 8x8 microtile, BK=8, fp32 vector ALU.
// ---------------------------------------------------------------------------
__global__ __launch_bounds__(256) void gemm_qkv_kernel(
    const float* __restrict__ X, const float* __restrict__ W,
    float* __restrict__ Qo, float* __restrict__ Ko, float* __restrict__ Vo)
{
    const int KDIM = D_MODEL;     // 1024
    const int N    = 3*D_MODEL;   // 3072
    __shared__ float As[8][128];
    __shared__ float Bs[8][128];
    const int tid  = threadIdx.x;
    const int tx   = tid & 15;
    const int ty   = tid >> 4;
    const int row0 = blockIdx.y * 128;
    const int col0 = blockIdx.x * 128;
    const int a_row = tid >> 1;
    const int a_col = (tid & 1) << 2;
    const int b_row = tid >> 5;
    const int b_col = (tid & 31) << 2;
    float acc[8][8] = {};
    for (int k0 = 0; k0 < KDIM; k0 += 8) {
        float4 av = *(const float4*)&X[(size_t)(row0 + a_row)*KDIM + k0 + a_col];
        float4 bv = *(const float4*)&W[(size_t)(k0 + b_row)*N + col0 + b_col];
        As[a_col+0][a_row] = av.x;
        As[a_col+1][a_row] = av.y;
        As[a_col+2][a_row] = av.z;
        As[a_col+3][a_row] = av.w;
        *(float4*)&Bs[b_row][b_col] = bv;
        __syncthreads();
        #pragma unroll
        for (int k = 0; k < 8; ++k) {
            float a[8], b[8];
            *(float4*)&a[0] = *(const float4*)&As[k][ty*8];
            *(float4*)&a[4] = *(const float4*)&As[k][ty*8+4];
            *(float4*)&b[0] = *(const float4*)&Bs[k][tx*8];
            *(float4*)&b[4] = *(const float4*)&Bs[k][tx*8+4];
            #pragma unroll
            for (int i = 0; i < 8; ++i)
                #pragma unroll
                for (int j = 0; j < 8; ++j)
                    acc[i][j] = fmaf(a[i], b[j], acc[i][j]);
        }
        __syncthreads();
    }
    const int cbase = col0 + tx*8;
    const int which = cbase >> 10;
    const int rem   = cbase & 1023;
    const int h     = rem >> 6;
    const int dd    = rem & 63;
    float* dstBase = (which == 0) ? Qo : (which == 1) ? Ko : Vo;
    #pragma unroll
    for (int i = 0; i < 8; ++i) {
        const int r  = row0 + ty*8 + i;
        const int bb = r >> 11;        // batch
        const int ss = r & 2047;       // seq pos
        float* dst = dstBase + ((size_t)(bb*NHEAD + h)*SEQ + ss)*HD + dd;
        *(float4*)&dst[0] = make_float4(acc[i][0], acc[i][1], acc[i][2], acc[i][3]);
        *(float4*)&dst[4] = make_float4(acc[i][4], acc[i][5], acc[i][6], acc[i][7]);
    }
}

// ---------------------------------------------------------------------------
// K2 v2: causal flash attention, fp32, HD split 4-ways across lanes.
// Block = 256 threads = 64 query rows of one (b,h). Lane: ds=lane&3 owns
// dims [16ds,16ds+16), rl=lane>>2 is row-in-wave. QK dot reduced across the
// 4-lane group via shfl_xor(1),shfl_xor(2). K/V tiles of 32 keys in LDS.
// ---------------------------------------------------------------------------
__global__ __launch_bounds__(256, 4) void attn_kernel(
    const float* __restrict__ Q, const float* __restrict__ K,
    const float* __restrict__ V, float* __restrict__ AO)
{
    __shared__ float Ks[32*64];
    __shared__ float Vs[32*64];
    const int tid  = threadIdx.x;
    const int lane = tid & 63;
    const int wv   = tid >> 6;            // wave 0..3
    const int ds   = lane & 3;            // dim split
    const int rl   = lane >> 2;           // row in wave 0..15
    const int bh   = blockIdx.y;          // 0..31
    const int qt   = blockIdx.x;          // 64-row q tile, 0..31
    const int row  = qt*64 + wv*16 + rl;  // query row
    const int d0   = ds*16;

    const float* qp = Q + ((size_t)bh*SEQ + row)*HD + d0;
    float q[16];
    #pragma unroll
    for (int i = 0; i < 4; ++i)
        *(float4*)&q[i*4] = *(const float4*)&qp[i*4];
    float o[16];
    #pragma unroll
    for (int i = 0; i < 16; ++i) o[i] = 0.f;
    float m = -1e30f, l = 0.f;

    const int kend = qt*64 + 64;
    const int wave_max_row = qt*64 + wv*16 + 15;

    for (int kt = 0; kt < kend; kt += 32) {
        __syncthreads();                  // protect previous tile reads
        const float* ksrc = K + ((size_t)bh*SEQ + kt)*HD;
        const float* vsrc = V + ((size_t)bh*SEQ + kt)*HD;
        *(float4*)&Ks[tid*4]        = *(const float4*)&ksrc[tid*4];
        *(float4*)&Ks[1024 + tid*4] = *(const float4*)&ksrc[1024 + tid*4];
        *(float4*)&Vs[tid*4]        = *(const float4*)&vsrc[tid*4];
        *(float4*)&Vs[1024 + tid*4] = *(const float4*)&vsrc[1024 + tid*4];
        __syncthreads();
        if (kt > wave_max_row) continue;  // whole wave above diagonal; all
                                          // threads still reach top barrier
        float s[32];
        #pragma unroll
        for (int kk = 0; kk < 32; ++kk) {
            const float* kp = &Ks[kk*64 + d0];
            float s0 = 0.f, s1 = 0.f, s2 = 0.f, s3 = 0.f;
            #pragma unroll
            for (int i = 0; i < 4; ++i) {
                float4 k4 = *(const float4*)&kp[i*4];
                s0 = fmaf(k4.x, q[i*4+0], s0);
                s1 = fmaf(k4.y, q[i*4+1], s1);
                s2 = fmaf(k4.z, q[i*4+2], s2);
                s3 = fmaf(k4.w, q[i*4+3], s3);
            }
            float p = (s0+s1)+(s2+s3);
            p += __shfl_xor(p, 1);
            p += __shfl_xor(p, 2);        // all 4 lanes now hold full dot
            float sv = p * 0.125f;
            s[kk] = (kt + kk > row) ? -1e30f : sv;
        }
        float mt = s[0];
        #pragma unroll
        for (int kk = 1; kk < 32; ++kk) mt = fmaxf(mt, s[kk]);
        const float mnew  = fmaxf(m, mt);
        const float alpha = __expf(m - mnew);
        float psum = 0.f;
        #pragma unroll
        for (int kk = 0; kk < 32; ++kk) { s[kk] = __expf(s[kk]-mnew); psum += s[kk]; }
        l = l*alpha + psum;
        m = mnew;
        #pragma unroll
        for (int i = 0; i < 16; ++i) o[i] *= alpha;
        #pragma unroll
        for (int kk = 0; kk < 32; ++kk) {
            const float* vp = &Vs[kk*64 + d0];
            const float p = s[kk];
            #pragma unroll
            for (int i = 0; i < 4; ++i) {
                float4 v4 = *(const float4*)&vp[i*4];
                o[i*4+0] = fmaf(p, v4.x, o[i*4+0]);
                o[i*4+1] = fmaf(p, v4.y, o[i*4+1]);
                o[i*4+2] = fmaf(p, v4.z, o[i*4+2]);
                o[i*4+3] = fmaf(p, v4.w, o[i*4+3]);
            }
        }
    }
    const float inv = 1.f / l;
    const int bb = bh >> 4;
    const int h  = bh & 15;
    float* dst = AO + ((size_t)bb*SEQ + row)*D_MODEL + h*HD + d0;
    #pragma unroll
    for (int i = 0; i < 4; ++i)
        *(float4*)&dst[i*4] = make_float4(o[i*4+0]*inv, o[i*4+1]*inv,
                                          o[i*4+2]*inv, o[i*4+3]*inv);
}

// ---------------------------------------------------------------------------
// K3: out = AO @ w_out  (M=4096, K=1024, N=1024)
// ---------------------------------------------------------------------------
__global__ __launch_bounds__(256) void gemm_out_kernel(
    const float* __restrict__ A, const float* __restrict__ W,
    float* __restrict__ C)
{
    const int KDIM = D_MODEL;   // 1024
    const int N    = D_MODEL;   // 1024
    __shared__ float As[8][128];
    __shared__ float Bs[8][128];
    const int tid  = threadIdx.x;
    const int tx   = tid & 15;
    const int ty   = tid >> 4;
    const int row0 = blockIdx.y * 128;
    const int col0 = blockIdx.x * 128;
    const int a_row = tid >> 1;
    const int a_col = (tid & 1) << 2;
    const int b_row = tid >> 5;
    const int b_col = (tid & 31) << 2;
    float acc[8][8] = {};
    for (int k0 = 0; k0 < KDIM; k0 += 8) {
        float4 av = *(const float4*)&A[(size_t)(row0 + a_row)*KDIM + k0 + a_col];
        float4 bv = *(const float4*)&W[(size_t)(k0 + b_row)*N + col0 + b_col];
        As[a_col+0][a_row] = av.x;
        As[a_col+1][a_row] = av.y;
        As[a_col+2][a_row] = av.z;
        As[a_col+3][a_row] = av.w;
        *(float4*)&Bs[b_row][b_col] = bv;
        __syncthreads();
        #pragma unroll
        for (int k = 0; k < 8; ++k) {
            float a[8], b[8];
            *(float4*)&a[0] = *(const float4*)&As[k][ty*8];
            *(float4*)&a[4] = *(const float4*)&As[k][ty*8+4];
            *(float4*)&b[0] = *(const float4*)&Bs[k][tx*8];
            *(float4*)&b[4] = *(const float4*)&Bs[k][tx*8+4];
            #pragma unroll
            for (int i = 0; i < 8; ++i)
                #pragma unroll
                for (int j = 0; j < 8; ++j)
                    acc[i][j] = fmaf(a[i], b[j], acc[i][j]);
        }
        __syncthreads();
    }
    #pragma unroll
    for (int i = 0; i < 8; ++i) {
        const int r = row0 + ty*8 + i;
        float* dst = C + (size_t)r*N + col0 + tx*8;
        *(float4*)&dst[0] = make_float4(acc[i][0], acc[i][1], acc[i][2], acc[i][3]);
        *(float4*)&dst[4] = make_float4(acc[i][4], acc[i][5], acc[i][6], acc[i][7]);
    }
}

// ---------------------------------------------------------------------------
extern "C" void kernel_launch(void* const* d_in, const int* in_sizes, int n_in,
                              void* d_out, int out_size, void* d_ws, size_t ws_size,
                              hipStream_t stream)
{
    const float* x     = (const float*)d_in[0];   // (2,2048,1024)
    const float* w_qkv = (const float*)d_in[1];   // (1024,3072)
    const float* w_out = (const float*)d_in[2];   // (1024,1024)
    float* out = (float*)d_out;                   // (2,2048,1024)

    const size_t per = (size_t)BH * SEQ * HD;     // 4,194,304 floats
    float* Q  = (float*)d_ws;
    float* K  = Q + per;
    float* V  = K + per;
    float* AO = V + per;                          // (B,S,D) attn output

    // qkv projection: grid = (N/128, M/128) = (24, 32)
    gemm_qkv_kernel<<<dim3(24, 32), 256, 0, stream>>>(x, w_qkv, Q, K, V);
    // causal attention: grid = (S/64, B*H) = (32, 32)
    attn_kernel<<<dim3(SEQ/64, BH), 256, 0, stream>>>(Q, K, V, AO);
    // output projection: grid = (N/128, M/128) = (8, 32)
    gemm_out_kernel<<<dim3(8, 32), 256, 0, stream>>>(AO, w_out, out);
}